// Round 5
// baseline (599.087 us; speedup 1.0000x reference)
//
#include <hip/hip_runtime.h>
#include <stdint.h>

// ---------------------------------------------------------------------------
// MultiHeadAttention: B=8 S=1024 QKV=1024 H=16 E=64 OUT=1024.
// RESOLVED dtypes: inputs fp32 (r4: fp32-convert path eliminated r1-r3 NaN),
// output fp32 (r4: absmax 0.2265 > max|ref| 0.156 == bf16-written-to-fp32-buf
// signature: first half ~neighbor values, second half zeros).
// Internals: bf16 MFMA with fp32 accumulation; fp32->bf16 conversion FUSED
// into GEMM LDS staging (no separate convert kernels).
// Pipeline: proj(q,k,v) -> bf16 Qp/Kp/Vp; flash_attn -> bf16 At;
//           outproj(At, Wo fp32, bo fp32) -> fp32 d_out.
// ws_size unknown -> host branch: big path 64 MB (6 dispatches) vs
// per-batch path 8 MB (40 dispatches).
// MFMA 16x16x32 bf16 fragment maps (HW-verified per guide m89/m91):
//   A[m=lane&15][k=(lane>>4)*8+j], B[k=(lane>>4)*8+j][n=lane&15],
//   D[row=(lane>>4)*4+r][col=lane&15]
// LDS tiles: row stride 72 bf16 (144 B), 16B-aligned ds_read_b128, 2-way max
// bank aliasing (free per m136).
// ---------------------------------------------------------------------------

typedef __bf16 bf16x8 __attribute__((ext_vector_type(8)));
typedef float f32x4 __attribute__((ext_vector_type(4)));

__device__ __forceinline__ ushort f2bf(float f) {
  uint32_t x = __float_as_uint(f);
  x += 0x7fff + ((x >> 16) & 1);  // RNE
  return (ushort)(x >> 16);
}
__device__ __forceinline__ bf16x8 ld8(const ushort* p) {
  union { uint4 u; bf16x8 b; } c;
  c.u = *reinterpret_cast<const uint4*>(p);
  return c.b;
}
// 16 contiguous fp32 -> 16 bf16 into contiguous LDS (two uint4 stores).
__device__ __forceinline__ void cvt16(const float* __restrict__ src,
                                      ushort* __restrict__ dst) {
  union { uint4 u[2]; ushort s[16]; } o;
#pragma unroll
  for (int i = 0; i < 4; ++i) {
    const float4 f = reinterpret_cast<const float4*>(src)[i];
    o.s[4 * i + 0] = f2bf(f.x);
    o.s[4 * i + 1] = f2bf(f.y);
    o.s[4 * i + 2] = f2bf(f.z);
    o.s[4 * i + 3] = f2bf(f.w);
  }
  reinterpret_cast<uint4*>(dst)[0] = o.u[0];
  reinterpret_cast<uint4*>(dst)[1] = o.u[1];
}
// 16 contiguous fp32 -> 16 bf16 into a register array (for scatter).
__device__ __forceinline__ void cvt16a(const float* __restrict__ src,
                                       ushort* __restrict__ out) {
#pragma unroll
  for (int i = 0; i < 4; ++i) {
    const float4 f = reinterpret_cast<const float4*>(src)[i];
    out[4 * i + 0] = f2bf(f.x);
    out[4 * i + 1] = f2bf(f.y);
    out[4 * i + 2] = f2bf(f.z);
    out[4 * i + 3] = f2bf(f.w);
  }
}

// --------------------------------------------------------------------------
// C[M][1024](bf16) = A[M][1024](fp32) @ W_h, W[H=16][QKV=1024][E=64](fp32),
// output col n = h*64+e. grid: dim3(16, M/64), block 256 (4 waves).
// W tile staged TRANSPOSED (scatter, 2-way LDS aliasing = free).
// --------------------------------------------------------------------------
__global__ __launch_bounds__(256) void proj(const float* __restrict__ A,
                                            const float* __restrict__ W,
                                            ushort* __restrict__ C) {
  __shared__ __align__(16) ushort As[64 * 72];
  __shared__ __align__(16) ushort Bs[64 * 72];
  const int h = blockIdx.x;
  const int m0 = blockIdx.y * 64;
  const int t = threadIdx.x;
  const int lane = t & 63;
  const int w = t >> 6;
  const int col = lane & 15;
  const int quad = lane >> 4;
  const int srow = t >> 2;        // 0..63
  const int sch = (t & 3) * 16;   // 0,16,32,48
  const int kk = t & 63;          // W staging: k within tile
  const int e0 = (t >> 6) * 16;   // W staging: e chunk

  f32x4 acc[4];
#pragma unroll
  for (int c = 0; c < 4; ++c) acc[c] = (f32x4){0.f, 0.f, 0.f, 0.f};

  const float* a_src = A + (size_t)(m0 + srow) * 1024 + sch;
  const float* w_src = W + (size_t)h * 65536 + (size_t)kk * 64 + e0;

  for (int k0 = 0; k0 < 1024; k0 += 64) {
    ushort wl[16];
    cvt16a(w_src + (size_t)k0 * 64, wl);
    cvt16(a_src + k0, &As[srow * 72 + sch]);
#pragma unroll
    for (int j = 0; j < 16; ++j) Bs[(e0 + j) * 72 + kk] = wl[j];
    __syncthreads();

    bf16x8 fa0 = ld8(&As[(w * 16 + col) * 72 + quad * 8]);
    bf16x8 fa1 = ld8(&As[(w * 16 + col) * 72 + 32 + quad * 8]);
#pragma unroll
    for (int c = 0; c < 4; ++c) {
      bf16x8 fb0 = ld8(&Bs[(c * 16 + col) * 72 + quad * 8]);
      bf16x8 fb1 = ld8(&Bs[(c * 16 + col) * 72 + 32 + quad * 8]);
      acc[c] = __builtin_amdgcn_mfma_f32_16x16x32_bf16(fa0, fb0, acc[c], 0, 0, 0);
      acc[c] = __builtin_amdgcn_mfma_f32_16x16x32_bf16(fa1, fb1, acc[c], 0, 0, 0);
    }
    __syncthreads();
  }

#pragma unroll
  for (int c = 0; c < 4; ++c) {
    const int n = h * 64 + c * 16 + col;
#pragma unroll
    for (int r = 0; r < 4; ++r) {
      const int m = m0 + w * 16 + quad * 4 + r;
      C[(size_t)m * 1024 + n] = f2bf(acc[c][r]);
    }
  }
}

// --------------------------------------------------------------------------
// C[M][1024](fp32) = A[M][1024](bf16) @ Wo[1024][1024](fp32)^T + bo(fp32).
// grid: dim3(16, M/64), block 256. C must not alias A.
// --------------------------------------------------------------------------
__global__ __launch_bounds__(256) void outproj(const ushort* __restrict__ A,
                                               const float* __restrict__ Wo,
                                               const float* __restrict__ bias,
                                               float* __restrict__ C) {
  __shared__ __align__(16) ushort As[64 * 72];
  __shared__ __align__(16) ushort Bs[64 * 72];
  const int n0 = blockIdx.x * 64;
  const int m0 = blockIdx.y * 64;
  const int t = threadIdx.x;
  const int lane = t & 63;
  const int w = t >> 6;
  const int col = lane & 15;
  const int quad = lane >> 4;
  const int srow = t >> 2;
  const int sch = (t & 3) * 16;

  f32x4 acc[4];
#pragma unroll
  for (int c = 0; c < 4; ++c) acc[c] = (f32x4){0.f, 0.f, 0.f, 0.f};

  const ushort* a_src = A + (size_t)(m0 + srow) * 1024 + sch;
  const float* b_src = Wo + (size_t)(n0 + srow) * 1024 + sch;

  for (int k0 = 0; k0 < 1024; k0 += 64) {
    uint4 av0 = reinterpret_cast<const uint4*>(a_src + k0)[0];
    uint4 av1 = reinterpret_cast<const uint4*>(a_src + k0)[1];
    cvt16(b_src + k0, &Bs[srow * 72 + sch]);
    reinterpret_cast<uint4*>(&As[srow * 72 + sch])[0] = av0;
    reinterpret_cast<uint4*>(&As[srow * 72 + sch])[1] = av1;
    __syncthreads();

    bf16x8 fa0 = ld8(&As[(w * 16 + col) * 72 + quad * 8]);
    bf16x8 fa1 = ld8(&As[(w * 16 + col) * 72 + 32 + quad * 8]);
#pragma unroll
    for (int c = 0; c < 4; ++c) {
      bf16x8 fb0 = ld8(&Bs[(c * 16 + col) * 72 + quad * 8]);
      bf16x8 fb1 = ld8(&Bs[(c * 16 + col) * 72 + 32 + quad * 8]);
      acc[c] = __builtin_amdgcn_mfma_f32_16x16x32_bf16(fa0, fb0, acc[c], 0, 0, 0);
      acc[c] = __builtin_amdgcn_mfma_f32_16x16x32_bf16(fa1, fb1, acc[c], 0, 0, 0);
    }
    __syncthreads();
  }

#pragma unroll
  for (int c = 0; c < 4; ++c) {
    const int n = n0 + c * 16 + col;
    const float bv = bias[n];
#pragma unroll
    for (int r = 0; r < 4; ++r) {
      const int m = m0 + w * 16 + quad * 4 + r;
      C[(size_t)m * 1024 + n] = acc[c][r] + bv;
    }
  }
}

// --------------------------------------------------------------------------
// Flash attention (bf16 in/out). Q,K,V,O: [rows][H*E], row = b*1024+s.
// grid: nblocks = rows/64*16 -> (b, h, qtile). block 256.
// --------------------------------------------------------------------------
__global__ __launch_bounds__(256) void flash_attn(const ushort* __restrict__ Q,
                                                  const ushort* __restrict__ K,
                                                  const ushort* __restrict__ V,
                                                  ushort* __restrict__ O) {
  __shared__ __align__(16) ushort Qs[64 * 72];
  __shared__ __align__(16) ushort Ks[64 * 72];
  __shared__ __align__(16) ushort Vt[64 * 72];
  __shared__ __align__(16) ushort Ps[64 * 72];
  const int bid = blockIdx.x;
  const int b = bid >> 8;
  const int h = (bid >> 4) & 15;
  const int qt = bid & 15;
  const int t = threadIdx.x;
  const int lane = t & 63;
  const int w = t >> 6;
  const int col = lane & 15;
  const int quad = lane >> 4;
  const int srow = t >> 2;
  const int sch = (t & 3) * 16;

  const size_t base = (size_t)b * 1024 * 1024 + h * 64;

  {
    const ushort* src = Q + base + (size_t)(qt * 64 + srow) * 1024 + sch;
    uint4 v0 = reinterpret_cast<const uint4*>(src)[0];
    uint4 v1 = reinterpret_cast<const uint4*>(src)[1];
    reinterpret_cast<uint4*>(&Qs[srow * 72 + sch])[0] = v0;
    reinterpret_cast<uint4*>(&Qs[srow * 72 + sch])[1] = v1;
  }
  __syncthreads();
  const bf16x8 qa0 = ld8(&Qs[(w * 16 + col) * 72 + quad * 8]);
  const bf16x8 qa1 = ld8(&Qs[(w * 16 + col) * 72 + 32 + quad * 8]);

  f32x4 o0 = {0.f, 0.f, 0.f, 0.f}, o1 = o0, o2 = o0, o3 = o0;
  float m_r[4] = {-1e30f, -1e30f, -1e30f, -1e30f};
  float l_r[4] = {0.f, 0.f, 0.f, 0.f};
  const float scale = 0.03125f;  // 1/sqrt(1024)

  for (int kt = 0; kt < 16; ++kt) {
    const ushort* ksrc = K + base + (size_t)(kt * 64 + srow) * 1024 + sch;
    uint4 kv0 = reinterpret_cast<const uint4*>(ksrc)[0];
    uint4 kv1 = reinterpret_cast<const uint4*>(ksrc)[1];
    const int vs = t & 63;
    const int ve = (t >> 6) * 16;
    const ushort* vsrc = V + base + (size_t)(kt * 64 + vs) * 1024 + ve;
    union { uint4 u[2]; ushort s[16]; } vv;
    vv.u[0] = reinterpret_cast<const uint4*>(vsrc)[0];
    vv.u[1] = reinterpret_cast<const uint4*>(vsrc)[1];
    reinterpret_cast<uint4*>(&Ks[srow * 72 + sch])[0] = kv0;
    reinterpret_cast<uint4*>(&Ks[srow * 72 + sch])[1] = kv1;
#pragma unroll
    for (int j = 0; j < 16; ++j) Vt[(ve + j) * 72 + vs] = vv.s[j];
    __syncthreads();

    f32x4 sc[4];
#pragma unroll
    for (int c = 0; c < 4; ++c) {
      bf16x8 kb0 = ld8(&Ks[(c * 16 + col) * 72 + quad * 8]);
      bf16x8 kb1 = ld8(&Ks[(c * 16 + col) * 72 + 32 + quad * 8]);
      f32x4 z = {0.f, 0.f, 0.f, 0.f};
      z = __builtin_amdgcn_mfma_f32_16x16x32_bf16(qa0, kb0, z, 0, 0, 0);
      z = __builtin_amdgcn_mfma_f32_16x16x32_bf16(qa1, kb1, z, 0, 0, 0);
      sc[c] = z * scale;
    }

#pragma unroll
    for (int r = 0; r < 4; ++r) {
      float mx = fmaxf(fmaxf(sc[0][r], sc[1][r]), fmaxf(sc[2][r], sc[3][r]));
      mx = fmaxf(mx, __shfl_xor(mx, 1));
      mx = fmaxf(mx, __shfl_xor(mx, 2));
      mx = fmaxf(mx, __shfl_xor(mx, 4));
      mx = fmaxf(mx, __shfl_xor(mx, 8));
      const float m_new = fmaxf(m_r[r], mx);
      const float alpha = __expf(m_r[r] - m_new);
      const float p0 = __expf(sc[0][r] - m_new);
      const float p1 = __expf(sc[1][r] - m_new);
      const float p2 = __expf(sc[2][r] - m_new);
      const float p3 = __expf(sc[3][r] - m_new);
      float rs = (p0 + p1) + (p2 + p3);
      rs += __shfl_xor(rs, 1);
      rs += __shfl_xor(rs, 2);
      rs += __shfl_xor(rs, 4);
      rs += __shfl_xor(rs, 8);
      l_r[r] = l_r[r] * alpha + rs;
      m_r[r] = m_new;
      o0[r] *= alpha; o1[r] *= alpha; o2[r] *= alpha; o3[r] *= alpha;
      const int prow = (w * 16 + quad * 4 + r) * 72;
      Ps[prow + 0 + col] = f2bf(p0);
      Ps[prow + 16 + col] = f2bf(p1);
      Ps[prow + 32 + col] = f2bf(p2);
      Ps[prow + 48 + col] = f2bf(p3);
    }
    __syncthreads();

    const bf16x8 pa0 = ld8(&Ps[(w * 16 + col) * 72 + quad * 8]);
    const bf16x8 pa1 = ld8(&Ps[(w * 16 + col) * 72 + 32 + quad * 8]);
#pragma unroll
    for (int c = 0; c < 4; ++c) {
      bf16x8 vb0 = ld8(&Vt[(c * 16 + col) * 72 + quad * 8]);
      bf16x8 vb1 = ld8(&Vt[(c * 16 + col) * 72 + 32 + quad * 8]);
      f32x4* oc = (c == 0) ? &o0 : (c == 1) ? &o1 : (c == 2) ? &o2 : &o3;
      *oc = __builtin_amdgcn_mfma_f32_16x16x32_bf16(pa0, vb0, *oc, 0, 0, 0);
      *oc = __builtin_amdgcn_mfma_f32_16x16x32_bf16(pa1, vb1, *oc, 0, 0, 0);
    }
    __syncthreads();
  }

#pragma unroll
  for (int r = 0; r < 4; ++r) {
    const float inv = 1.f / l_r[r];
    const size_t row = base + (size_t)(qt * 64 + w * 16 + quad * 4 + r) * 1024;
    O[row + 0 + col] = f2bf(o0[r] * inv);
    O[row + 16 + col] = f2bf(o1[r] * inv);
    O[row + 32 + col] = f2bf(o2[r] * inv);
    O[row + 48 + col] = f2bf(o3[r] * inv);
  }
}

// --------------------------------------------------------------------------
extern "C" void kernel_launch(void* const* d_in, const int* in_sizes, int n_in,
                              void* d_out, int out_size, void* d_ws, size_t ws_size,
                              hipStream_t stream) {
  const float* q = (const float*)d_in[0];
  const float* k = (const float*)d_in[1];
  const float* v = (const float*)d_in[2];
  const float* Wq = (const float*)d_in[3];
  const float* Wk = (const float*)d_in[4];
  const float* Wv = (const float*)d_in[5];
  const float* Wo = (const float*)d_in[6];
  const float* bo = (const float*)d_in[7];
  float* out = (float*)d_out;
  ushort* ws = (ushort*)d_ws;

  const size_t M8 = 8u << 20;  // 8M bf16 elements = 16 MB
  const size_t M1 = 1u << 20;  // 1M bf16 elements = 2 MB

  if (ws_size >= (64ull << 20)) {
    // Big path: 64 MB ws, 6 dispatches.
    ushort* Qp = ws;
    ushort* Kp = ws + M8;
    ushort* Vp = ws + 2 * M8;
    ushort* At = ws + 3 * M8;
    proj<<<dim3(16, 128), 256, 0, stream>>>(q, Wq, Qp);
    proj<<<dim3(16, 128), 256, 0, stream>>>(k, Wk, Kp);
    proj<<<dim3(16, 128), 256, 0, stream>>>(v, Wv, Vp);
    flash_attn<<<2048, 256, 0, stream>>>(Qp, Kp, Vp, At);
    outproj<<<dim3(16, 128), 256, 0, stream>>>(At, Wo, bo, out);
  } else {
    // Small path: 8 MB ws, per-batch, 40 dispatches.
    ushort* Qb = ws;
    ushort* Kb = ws + M1;
    ushort* Vb = ws + 2 * M1;
    ushort* Ab = ws + 3 * M1;
    for (int b = 0; b < 8; ++b) {
      const size_t off = (size_t)b * (1u << 20);  // 1M elements per batch
      proj<<<dim3(16, 16), 256, 0, stream>>>(q + off, Wq, Qb);
      proj<<<dim3(16, 16), 256, 0, stream>>>(k + off, Wk, Kb);
      proj<<<dim3(16, 16), 256, 0, stream>>>(v + off, Wv, Vb);
      flash_attn<<<256, 256, 0, stream>>>(Qb, Kb, Vb, Ab);
      outproj<<<dim3(16, 16), 256, 0, stream>>>(Ab, Wo, bo, out + off);
    }
  }
}

// Round 7
// 466.828 us; speedup vs baseline: 1.2833x; 1.2833x over previous
//
#include <hip/hip_runtime.h>
#include <stdint.h>

// ---------------------------------------------------------------------------
// MultiHeadAttention: B=8 S=1024 QKV=1024 H=16 E=64 OUT=1024.
// fp32 in / fp32 out (resolved r4/r5), bf16 MFMA internals, fp32 accum.
// R7 = R6 with the staging-coverage bug fixed: 128-row tiles have 2 thr/row,
// so each thread stages 32 elements (4x uint4), not 16. R6 left half of
// every LDS tile uninitialized -> NaN. COVERAGE RULE: threads x bytes/thread
// must equal tile bytes — check per staging site.
// ws (>=64MB confirmed r5): [Qp 16][Kp 16][Vp 16][WqT 2|WkT 2|WvT 2|WoB 2]
// flash runs in-place on Qp (block-disjoint regions).
// MFMA 16x16x32 bf16 maps (HW-verified m89/m91):
//   A[m=lane&15][k=quad*8+j], B[k=quad*8+j][n=lane&15], D[row=quad*4+r][col]
// LDS: row stride 72 ushort (144B, 16B-aligned ds_read_b128, 2-way max).
// ---------------------------------------------------------------------------

typedef __bf16 bf16x8 __attribute__((ext_vector_type(8)));
typedef float f32x4 __attribute__((ext_vector_type(4)));

__device__ __forceinline__ ushort f2bf(float f) {
  uint32_t x = __float_as_uint(f);
  x += 0x7fff + ((x >> 16) & 1);  // RNE
  return (ushort)(x >> 16);
}
__device__ __forceinline__ bf16x8 ld8(const ushort* p) {
  union { uint4 u; bf16x8 b; } c;
  c.u = *reinterpret_cast<const uint4*>(p);
  return c.b;
}
// 16 contiguous fp32 -> 16 bf16 (two uint4 stores; works for LDS or global)
__device__ __forceinline__ void cvt16(const float* __restrict__ src,
                                      ushort* __restrict__ dst) {
  union { uint4 u[2]; ushort s[16]; } o;
#pragma unroll
  for (int i = 0; i < 4; ++i) {
    const float4 f = reinterpret_cast<const float4*>(src)[i];
    o.s[4 * i + 0] = f2bf(f.x);
    o.s[4 * i + 1] = f2bf(f.y);
    o.s[4 * i + 2] = f2bf(f.z);
    o.s[4 * i + 3] = f2bf(f.w);
  }
  reinterpret_cast<uint4*>(dst)[0] = o.u[0];
  reinterpret_cast<uint4*>(dst)[1] = o.u[1];
}

// --------------------------------------------------------------------------
// W[16][1024][64] fp32 -> WT[1024][1024] bf16 (WT[n=h*64+e][k]).
// grid 256 = (h, ktile), block 256. Coverage: 256 thr x 16 = 64x64 tile. OK
// --------------------------------------------------------------------------
__global__ __launch_bounds__(256) void prep_wt(const float* __restrict__ W,
                                               ushort* __restrict__ WT) {
  __shared__ __align__(16) ushort tile[64 * 72];
  const int h = blockIdx.x >> 4;
  const int kt = blockIdx.x & 15;
  const int t = threadIdx.x;
  const int row = t >> 2;        // k within tile
  const int ch = (t & 3) * 16;   // e chunk
  cvt16(W + ((size_t)h * 1024 + kt * 64 + row) * 64 + ch, &tile[row * 72 + ch]);
  __syncthreads();
  const int e = t >> 2;
  const int kc = (t & 3) * 16;
  ushort vals[16];
#pragma unroll
  for (int j = 0; j < 16; ++j) vals[j] = tile[(kc + j) * 72 + e];
  ushort* dst = WT + (size_t)(h * 64 + e) * 1024 + kt * 64 + kc;
  reinterpret_cast<uint4*>(dst)[0] = *reinterpret_cast<uint4*>(&vals[0]);
  reinterpret_cast<uint4*>(dst)[1] = *reinterpret_cast<uint4*>(&vals[8]);
}

// Wo[1024][1024] fp32 -> bf16 (no transpose; already [N][K]). grid 256.
__global__ __launch_bounds__(256) void cvt_wo(const float* __restrict__ Wo,
                                              ushort* __restrict__ WoB) {
  const int i = (blockIdx.x * 256 + threadIdx.x) * 16;
  cvt16(Wo + i, WoB + i);
}

// --------------------------------------------------------------------------
// C[8192][1024] bf16 = A[8192][1024] fp32 @ Bt[1024][1024] bf16 ^T.
// 128x128 tile, BK=64, 256 thr (4 waves, 2x2 wave grid, 4x4 MFMA each).
// Staging coverage: 2 thr/row -> 32 elems/thread (A: 2x cvt16, B: 4x uint4).
// grid dim3(8, 64).
// --------------------------------------------------------------------------
__global__ __launch_bounds__(256) void gemm_a32(const float* __restrict__ A,
                                                const ushort* __restrict__ Bt,
                                                ushort* __restrict__ C) {
  __shared__ __align__(16) ushort As[128 * 72];
  __shared__ __align__(16) ushort Bs[128 * 72];
  const int n0 = blockIdx.x * 128;
  const int m0 = blockIdx.y * 128;
  const int t = threadIdx.x;
  const int lane = t & 63;
  const int w = t >> 6;
  const int wm = w >> 1, wn = w & 1;
  const int col = lane & 15;
  const int quad = lane >> 4;
  const int srow = t >> 1;        // 0..127
  const int sc0 = (t & 1) * 32;   // 0 or 32

  f32x4 acc[4][4];
#pragma unroll
  for (int i = 0; i < 4; ++i)
#pragma unroll
    for (int j = 0; j < 4; ++j) acc[i][j] = (f32x4){0.f, 0.f, 0.f, 0.f};

  const float* a_src = A + (size_t)(m0 + srow) * 1024 + sc0;
  const ushort* b_src = Bt + (size_t)(n0 + srow) * 1024 + sc0;

  for (int k0 = 0; k0 < 1024; k0 += 64) {
    uint4 b0 = reinterpret_cast<const uint4*>(b_src + k0)[0];
    uint4 b1 = reinterpret_cast<const uint4*>(b_src + k0)[1];
    uint4 b2 = reinterpret_cast<const uint4*>(b_src + k0)[2];
    uint4 b3 = reinterpret_cast<const uint4*>(b_src + k0)[3];
    cvt16(a_src + k0, &As[srow * 72 + sc0]);
    cvt16(a_src + k0 + 16, &As[srow * 72 + sc0 + 16]);
    reinterpret_cast<uint4*>(&Bs[srow * 72 + sc0])[0] = b0;
    reinterpret_cast<uint4*>(&Bs[srow * 72 + sc0])[1] = b1;
    reinterpret_cast<uint4*>(&Bs[srow * 72 + sc0])[2] = b2;
    reinterpret_cast<uint4*>(&Bs[srow * 72 + sc0])[3] = b3;
    __syncthreads();

#pragma unroll
    for (int half = 0; half < 2; ++half) {
      bf16x8 af[4], bf[4];
#pragma unroll
      for (int i = 0; i < 4; ++i)
        af[i] = ld8(&As[(wm * 64 + i * 16 + col) * 72 + half * 32 + quad * 8]);
#pragma unroll
      for (int j = 0; j < 4; ++j)
        bf[j] = ld8(&Bs[(wn * 64 + j * 16 + col) * 72 + half * 32 + quad * 8]);
#pragma unroll
      for (int i = 0; i < 4; ++i)
#pragma unroll
        for (int j = 0; j < 4; ++j)
          acc[i][j] = __builtin_amdgcn_mfma_f32_16x16x32_bf16(af[i], bf[j],
                                                              acc[i][j], 0, 0, 0);
    }
    __syncthreads();
  }

#pragma unroll
  for (int i = 0; i < 4; ++i)
#pragma unroll
    for (int j = 0; j < 4; ++j) {
      const int n = n0 + wn * 64 + j * 16 + col;
#pragma unroll
      for (int r = 0; r < 4; ++r) {
        const int m = m0 + wm * 64 + i * 16 + quad * 4 + r;
        C[(size_t)m * 1024 + n] = f2bf(acc[i][j][r]);
      }
    }
}

// --------------------------------------------------------------------------
// C[8192][1024] fp32 = A[8192][1024] bf16 @ Bt[1024][1024] bf16 ^T + bias.
// Same tiling; staging 32 elems/thread for BOTH operands (4x uint4 each).
// grid dim3(8, 64).
// --------------------------------------------------------------------------
__global__ __launch_bounds__(256) void gemm_a16(const ushort* __restrict__ A,
                                                const ushort* __restrict__ Bt,
                                                const float* __restrict__ bias,
                                                float* __restrict__ C) {
  __shared__ __align__(16) ushort As[128 * 72];
  __shared__ __align__(16) ushort Bs[128 * 72];
  const int n0 = blockIdx.x * 128;
  const int m0 = blockIdx.y * 128;
  const int t = threadIdx.x;
  const int lane = t & 63;
  const int w = t >> 6;
  const int wm = w >> 1, wn = w & 1;
  const int col = lane & 15;
  const int quad = lane >> 4;
  const int srow = t >> 1;
  const int sc0 = (t & 1) * 32;

  f32x4 acc[4][4];
#pragma unroll
  for (int i = 0; i < 4; ++i)
#pragma unroll
    for (int j = 0; j < 4; ++j) acc[i][j] = (f32x4){0.f, 0.f, 0.f, 0.f};

  const ushort* a_src = A + (size_t)(m0 + srow) * 1024 + sc0;
  const ushort* b_src = Bt + (size_t)(n0 + srow) * 1024 + sc0;

  for (int k0 = 0; k0 < 1024; k0 += 64) {
    uint4 a0 = reinterpret_cast<const uint4*>(a_src + k0)[0];
    uint4 a1 = reinterpret_cast<const uint4*>(a_src + k0)[1];
    uint4 a2 = reinterpret_cast<const uint4*>(a_src + k0)[2];
    uint4 a3 = reinterpret_cast<const uint4*>(a_src + k0)[3];
    uint4 b0 = reinterpret_cast<const uint4*>(b_src + k0)[0];
    uint4 b1 = reinterpret_cast<const uint4*>(b_src + k0)[1];
    uint4 b2 = reinterpret_cast<const uint4*>(b_src + k0)[2];
    uint4 b3 = reinterpret_cast<const uint4*>(b_src + k0)[3];
    reinterpret_cast<uint4*>(&As[srow * 72 + sc0])[0] = a0;
    reinterpret_cast<uint4*>(&As[srow * 72 + sc0])[1] = a1;
    reinterpret_cast<uint4*>(&As[srow * 72 + sc0])[2] = a2;
    reinterpret_cast<uint4*>(&As[srow * 72 + sc0])[3] = a3;
    reinterpret_cast<uint4*>(&Bs[srow * 72 + sc0])[0] = b0;
    reinterpret_cast<uint4*>(&Bs[srow * 72 + sc0])[1] = b1;
    reinterpret_cast<uint4*>(&Bs[srow * 72 + sc0])[2] = b2;
    reinterpret_cast<uint4*>(&Bs[srow * 72 + sc0])[3] = b3;
    __syncthreads();

#pragma unroll
    for (int half = 0; half < 2; ++half) {
      bf16x8 af[4], bf[4];
#pragma unroll
      for (int i = 0; i < 4; ++i)
        af[i] = ld8(&As[(wm * 64 + i * 16 + col) * 72 + half * 32 + quad * 8]);
#pragma unroll
      for (int j = 0; j < 4; ++j)
        bf[j] = ld8(&Bs[(wn * 64 + j * 16 + col) * 72 + half * 32 + quad * 8]);
#pragma unroll
      for (int i = 0; i < 4; ++i)
#pragma unroll
        for (int j = 0; j < 4; ++j)
          acc[i][j] = __builtin_amdgcn_mfma_f32_16x16x32_bf16(af[i], bf[j],
                                                              acc[i][j], 0, 0, 0);
    }
    __syncthreads();
  }

#pragma unroll
  for (int i = 0; i < 4; ++i)
#pragma unroll
    for (int j = 0; j < 4; ++j) {
      const int n = n0 + wn * 64 + j * 16 + col;
      const float bv = bias[n];
#pragma unroll
      for (int r = 0; r < 4; ++r) {
        const int m = m0 + wm * 64 + i * 16 + quad * 4 + r;
        C[(size_t)m * 1024 + n] = acc[i][j][r] + bv;
      }
    }
}

// --------------------------------------------------------------------------
// Flash attention, 128-row q-tiles. Q,K,V,O bf16 [8192][1024], O may alias Q
// (block-disjoint regions; Q read to LDS/regs before O write).
// grid 1024: pair=bid&127 -> (b=pair>>4, h=pair&15), qt=bid>>7 (XCD swizzle:
// same (b,h) => same bid%8 => same XCD L2 for K/V reuse).
// block 256 (4 waves); wave w owns rows w*32..w*32+31 (2 groups of 16).
// LDS: QP union (Qs at init, Ps in loop) + Ks + Vt = 36 KB.
// Q staging coverage: 2 thr/row -> 32 ushorts/thread (4x uint4).
// --------------------------------------------------------------------------
__global__ __launch_bounds__(256) void flash_attn(const ushort* __restrict__ Q,
                                                  const ushort* __restrict__ K,
                                                  const ushort* __restrict__ V,
                                                  ushort* __restrict__ O) {
  __shared__ __align__(16) ushort QP[128 * 72];
  __shared__ __align__(16) ushort Ks[64 * 72];
  __shared__ __align__(16) ushort Vt[64 * 72];
  const int pair = blockIdx.x & 127;
  const int b = pair >> 4;
  const int h = pair & 15;
  const int qt = blockIdx.x >> 7;
  const int t = threadIdx.x;
  const int lane = t & 63;
  const int w = t >> 6;
  const int col = lane & 15;
  const int quad = lane >> 4;

  const size_t base = (size_t)b * 1024 * 1024 + h * 64;
  const int qrow0 = qt * 128;

  // stage Q (128 rows x 64 cols): 32 ushorts per thread
  {
    const int row = t >> 1;
    const int c0 = (t & 1) * 32;
    const ushort* src = Q + base + (size_t)(qrow0 + row) * 1024 + c0;
    uint4 v0 = reinterpret_cast<const uint4*>(src)[0];
    uint4 v1 = reinterpret_cast<const uint4*>(src)[1];
    uint4 v2 = reinterpret_cast<const uint4*>(src)[2];
    uint4 v3 = reinterpret_cast<const uint4*>(src)[3];
    reinterpret_cast<uint4*>(&QP[row * 72 + c0])[0] = v0;
    reinterpret_cast<uint4*>(&QP[row * 72 + c0])[1] = v1;
    reinterpret_cast<uint4*>(&QP[row * 72 + c0])[2] = v2;
    reinterpret_cast<uint4*>(&QP[row * 72 + c0])[3] = v3;
  }
  __syncthreads();
  bf16x8 qa[2][2];
#pragma unroll
  for (int g = 0; g < 2; ++g)
#pragma unroll
    for (int half = 0; half < 2; ++half)
      qa[g][half] =
          ld8(&QP[(w * 32 + g * 16 + col) * 72 + half * 32 + quad * 8]);
  // qa reads complete before the first kt-staging barrier below, so reusing
  // QP as the P buffer afterwards is race-free (P writes happen only after
  // every wave has passed that barrier, hence after every qa read).

  f32x4 o_[2][4];
#pragma unroll
  for (int g = 0; g < 2; ++g)
#pragma unroll
    for (int c = 0; c < 4; ++c) o_[g][c] = (f32x4){0.f, 0.f, 0.f, 0.f};
  float m_r[2][4], l_r[2][4];
#pragma unroll
  for (int g = 0; g < 2; ++g)
#pragma unroll
    for (int r = 0; r < 4; ++r) { m_r[g][r] = -1e30f; l_r[g][r] = 0.f; }
  const float scale = 0.03125f;  // 1/sqrt(1024)

  for (int kt = 0; kt < 16; ++kt) {
    // stage K (coalesced rows; 4 thr/row x 16) and V transposed
    {
      const int srow = t >> 2;
      const int sch = (t & 3) * 16;
      const ushort* ksrc = K + base + (size_t)(kt * 64 + srow) * 1024 + sch;
      uint4 kv0 = reinterpret_cast<const uint4*>(ksrc)[0];
      uint4 kv1 = reinterpret_cast<const uint4*>(ksrc)[1];
      const int vs = t & 63;
      const int ve = (t >> 6) * 16;
      const ushort* vsrc = V + base + (size_t)(kt * 64 + vs) * 1024 + ve;
      union { uint4 u[2]; ushort s[16]; } vv;
      vv.u[0] = reinterpret_cast<const uint4*>(vsrc)[0];
      vv.u[1] = reinterpret_cast<const uint4*>(vsrc)[1];
      reinterpret_cast<uint4*>(&Ks[srow * 72 + sch])[0] = kv0;
      reinterpret_cast<uint4*>(&Ks[srow * 72 + sch])[1] = kv1;
#pragma unroll
      for (int j = 0; j < 16; ++j) Vt[(ve + j) * 72 + vs] = vv.s[j];
    }
    __syncthreads();

    // S = scale * Q K^T : both row-groups share the K fragments
    f32x4 sc[2][4];
#pragma unroll
    for (int c = 0; c < 4; ++c) {
      bf16x8 kb0 = ld8(&Ks[(c * 16 + col) * 72 + quad * 8]);
      bf16x8 kb1 = ld8(&Ks[(c * 16 + col) * 72 + 32 + quad * 8]);
#pragma unroll
      for (int g = 0; g < 2; ++g) {
        f32x4 z = {0.f, 0.f, 0.f, 0.f};
        z = __builtin_amdgcn_mfma_f32_16x16x32_bf16(qa[g][0], kb0, z, 0, 0, 0);
        z = __builtin_amdgcn_mfma_f32_16x16x32_bf16(qa[g][1], kb1, z, 0, 0, 0);
        sc[g][c] = z * scale;
      }
    }

    // online softmax; P -> QP (bf16)
#pragma unroll
    for (int g = 0; g < 2; ++g)
#pragma unroll
      for (int r = 0; r < 4; ++r) {
        float mx = fmaxf(fmaxf(sc[g][0][r], sc[g][1][r]),
                         fmaxf(sc[g][2][r], sc[g][3][r]));
        mx = fmaxf(mx, __shfl_xor(mx, 1));
        mx = fmaxf(mx, __shfl_xor(mx, 2));
        mx = fmaxf(mx, __shfl_xor(mx, 4));
        mx = fmaxf(mx, __shfl_xor(mx, 8));
        const float m_new = fmaxf(m_r[g][r], mx);
        const float alpha = __expf(m_r[g][r] - m_new);
        const float p0 = __expf(sc[g][0][r] - m_new);
        const float p1 = __expf(sc[g][1][r] - m_new);
        const float p2 = __expf(sc[g][2][r] - m_new);
        const float p3 = __expf(sc[g][3][r] - m_new);
        float rs = (p0 + p1) + (p2 + p3);
        rs += __shfl_xor(rs, 1);
        rs += __shfl_xor(rs, 2);
        rs += __shfl_xor(rs, 4);
        rs += __shfl_xor(rs, 8);
        l_r[g][r] = l_r[g][r] * alpha + rs;
        m_r[g][r] = m_new;
        o_[g][0][r] *= alpha; o_[g][1][r] *= alpha;
        o_[g][2][r] *= alpha; o_[g][3][r] *= alpha;
        const int prow = (w * 32 + g * 16 + quad * 4 + r) * 72;
        QP[prow + 0 + col] = f2bf(p0);
        QP[prow + 16 + col] = f2bf(p1);
        QP[prow + 32 + col] = f2bf(p2);
        QP[prow + 48 + col] = f2bf(p3);
      }
    __syncthreads();

    // O += P V : both row-groups share the V fragments
    bf16x8 pa[2][2];
#pragma unroll
    for (int g = 0; g < 2; ++g)
#pragma unroll
      for (int half = 0; half < 2; ++half)
        pa[g][half] =
            ld8(&QP[(w * 32 + g * 16 + col) * 72 + half * 32 + quad * 8]);
#pragma unroll
    for (int c = 0; c < 4; ++c) {
      bf16x8 vb0 = ld8(&Vt[(c * 16 + col) * 72 + quad * 8]);
      bf16x8 vb1 = ld8(&Vt[(c * 16 + col) * 72 + 32 + quad * 8]);
#pragma unroll
      for (int g = 0; g < 2; ++g) {
        o_[g][c] = __builtin_amdgcn_mfma_f32_16x16x32_bf16(pa[g][0], vb0,
                                                           o_[g][c], 0, 0, 0);
        o_[g][c] = __builtin_amdgcn_mfma_f32_16x16x32_bf16(pa[g][1], vb1,
                                                           o_[g][c], 0, 0, 0);
      }
    }
    __syncthreads();
  }

#pragma unroll
  for (int g = 0; g < 2; ++g)
#pragma unroll
    for (int r = 0; r < 4; ++r) {
      const float inv = 1.f / l_r[g][r];
      const size_t row =
          base + (size_t)(qrow0 + w * 32 + g * 16 + quad * 4 + r) * 1024;
      O[row + 0 + col] = f2bf(o_[g][0][r] * inv);
      O[row + 16 + col] = f2bf(o_[g][1][r] * inv);
      O[row + 32 + col] = f2bf(o_[g][2][r] * inv);
      O[row + 48 + col] = f2bf(o_[g][3][r] * inv);
    }
}

// --------------------------------------------------------------------------
extern "C" void kernel_launch(void* const* d_in, const int* in_sizes, int n_in,
                              void* d_out, int out_size, void* d_ws, size_t ws_size,
                              hipStream_t stream) {
  const float* q = (const float*)d_in[0];
  const float* k = (const float*)d_in[1];
  const float* v = (const float*)d_in[2];
  const float* Wq = (const float*)d_in[3];
  const float* Wk = (const float*)d_in[4];
  const float* Wv = (const float*)d_in[5];
  const float* Wo = (const float*)d_in[6];
  const float* bo = (const float*)d_in[7];
  float* out = (float*)d_out;
  ushort* ws = (ushort*)d_ws;

  const size_t M8 = 8u << 20;  // 8M bf16 = 16 MB
  const size_t M1 = 1u << 20;
  ushort* Qp = ws;                 // also flash output (in-place)
  ushort* Kp = ws + M8;
  ushort* Vp = ws + 2 * M8;
  ushort* WqT = ws + 3 * M8;
  ushort* WkT = WqT + M1;
  ushort* WvT = WkT + M1;
  ushort* WoB = WvT + M1;          // total 56 MB

  prep_wt<<<256, 256, 0, stream>>>(Wq, WqT);
  prep_wt<<<256, 256, 0, stream>>>(Wk, WkT);
  prep_wt<<<256, 256, 0, stream>>>(Wv, WvT);
  cvt_wo<<<256, 256, 0, stream>>>(Wo, WoB);

  gemm_a32<<<dim3(8, 64), 256, 0, stream>>>(q, WqT, Qp);
  gemm_a32<<<dim3(8, 64), 256, 0, stream>>>(k, WkT, Kp);
  gemm_a32<<<dim3(8, 64), 256, 0, stream>>>(v, WvT, Vp);

  flash_attn<<<1024, 256, 0, stream>>>(Qp, Kp, Vp, Qp);

  gemm_a16<<<dim3(8, 64), 256, 0, stream>>>(Qp, WoB, bo, out);
}